// Round 5
// baseline (108.747 us; speedup 1.0000x reference)
//
#include <hip/hip_runtime.h>
#include <hip/hip_bf16.h>

// PGExplainer edge-MLP:
//   logits[e] = relu(concat(emb[src], emb[dst]) @ W1 + b1) @ W2 + b2
// Restructured: A[n] = emb[n] @ W1[:64] + b1 ; B[n] = emb[n] @ W1[64:]
//   logits[e] = relu(A[src]+B[dst]) . W2 + b2
// AB[n*128 + j] bf16 (j<64 = A, j>=64 = B) lives in d_ws.
//
// R5 changes vs R4:
//  - precompute: W1 fragments via LDS transpose (coalesced global float4 in,
//    aligned ds_read_b128 frags out) instead of 128 strided scalar loads/wave;
//    C-tile staged in per-wave LDS then written as coalesced dwordx4 (was 32
//    scalar 2B stores/lane at 256B stride = 32x write amplification).
//    128 blocks (~6 tiles/wave) amortizes setup. nNodes%16==0 fast path.
//  - edge: 16 edges/wave-iter (4 gathers/lane in flight), explicit index
//    prefetch 1 iter ahead (breaks idx->gather serial chain), nontemporal
//    index loads + out stores (protect AB's L2 residency).

typedef __attribute__((ext_vector_type(8))) short bf16x8;
typedef __attribute__((ext_vector_type(4))) float f32x4;

__device__ __forceinline__ unsigned short f2bf(float f) {
    union { float f; unsigned int i; } v;
    v.f = f;
    unsigned int r = v.i + 0x7fffu + ((v.i >> 16) & 1u);  // RNE
    return (unsigned short)(r >> 16);
}

template <int N>
__device__ __forceinline__ float dpp_shr(float x) {
    return __int_as_float(__builtin_amdgcn_update_dpp(
        0, __float_as_int(x), 0x110 | N, 0xf, 0xf, true));
}

// MFMA GEMM: AB[50000 x 128] = E[50000 x 64] @ Wbig[64 x 128] (+ b1 cols<64)
// Wbig[k][j'] = j'<64 ? W1[k][j'] : W1[64+k][j'-64]
// Frag layouts (mfma_f32_16x16x32_bf16):
//   A: row = lane&15, k = (lane>>4)*8 + i (8 contiguous bf16)
//   B: col = lane&15, k = (lane>>4)*8 + i
//   D: col = lane&15, row = (lane>>4)*4 + reg   [verified m89]
__global__ __launch_bounds__(256) void precompute_ab(
    const float* __restrict__ emb, const float* __restrict__ W1,
    const float* __restrict__ b1, unsigned short* __restrict__ AB,
    int nNodes, int totalWaves)
{
    __shared__ unsigned short WT[128][72];        // WT[j'][k] bf16, pad to 72
    __shared__ unsigned short stage[4][16][136];  // per-wave 16x128 tile, 16B-aligned rows

    const int tid  = threadIdx.x;
    const int lane = tid & 63;
    const int wv   = tid >> 6;
    const int waveId = blockIdx.x * 4 + wv;
    const int c  = lane & 15;   // col selector (B/D), row selector (A)
    const int kb = lane >> 4;   // k-block 0..3

    // --- stage W1 transposed into LDS: Wbig col j' = W1 flat col ---
    // W1 flat: [128][64] fp32 row-major; Wbig[k][j'] = W1[j'<64 ? k : 64+k][j'%64]
    // WT[j'][k] holds Wbig col-major so fragment reads are contiguous in k.
    for (int p = tid; p < 2048; p += 256) {       // 2048 float4s = 32KB
        const float4 v = reinterpret_cast<const float4*>(W1)[p];
        const int k  = p >> 4;          // 0..127 row of W1
        const int j0 = (p & 15) * 4;    // 0..60 col of W1
        // W1 row k, cols j0..j0+3  ->  Wbig element (k<64 ? (k, j0') : (k-64, j0'+64))
        const int kk2 = (k < 64) ? k : (k - 64);
        const int jo  = (k < 64) ? 0 : 64;
        WT[jo + j0 + 0][kk2] = f2bf(v.x);
        WT[jo + j0 + 1][kk2] = f2bf(v.y);
        WT[jo + j0 + 2][kk2] = f2bf(v.z);
        WT[jo + j0 + 3][kk2] = f2bf(v.w);
    }
    __syncthreads();

    // --- B fragments from LDS: aligned ds_read_b128 ---
    bf16x8 wfrag[8][2];
    float bias[8];
#pragma unroll
    for (int nt = 0; nt < 8; ++nt) {
        const int jp = nt * 16 + c;
        bias[nt] = (jp < 64) ? b1[jp] : 0.f;
#pragma unroll
        for (int kk = 0; kk < 2; ++kk)
            wfrag[nt][kk] = *reinterpret_cast<const bf16x8*>(&WT[jp][kk * 32 + kb * 8]);
    }

    const int nTiles = (nNodes + 15) >> 4;
    for (int t = waveId; t < nTiles; t += totalWaves) {
        const int n0 = t * 16;
        // --- A fragments: 16 nodes x 64 k ---
        const int arow = n0 + c;
        const float* erow = emb + (size_t)((arow < nNodes) ? arow : (nNodes - 1)) * 64 + kb * 8;
        bf16x8 afrag[2];
#pragma unroll
        for (int kk = 0; kk < 2; ++kk) {
            const float4 f0 = *reinterpret_cast<const float4*>(erow + kk * 32);
            const float4 f1 = *reinterpret_cast<const float4*>(erow + kk * 32 + 4);
            afrag[kk][0] = (short)f2bf(f0.x); afrag[kk][1] = (short)f2bf(f0.y);
            afrag[kk][2] = (short)f2bf(f0.z); afrag[kk][3] = (short)f2bf(f0.w);
            afrag[kk][4] = (short)f2bf(f1.x); afrag[kk][5] = (short)f2bf(f1.y);
            afrag[kk][6] = (short)f2bf(f1.z); afrag[kk][7] = (short)f2bf(f1.w);
        }

        f32x4 acc[8];
#pragma unroll
        for (int nt = 0; nt < 8; ++nt) {
            acc[nt][0] = bias[nt]; acc[nt][1] = bias[nt];
            acc[nt][2] = bias[nt]; acc[nt][3] = bias[nt];
        }
#pragma unroll
        for (int kk = 0; kk < 2; ++kk)
#pragma unroll
            for (int nt = 0; nt < 8; ++nt)
                acc[nt] = __builtin_amdgcn_mfma_f32_16x16x32_bf16(
                    afrag[kk], wfrag[nt][kk], acc[nt], 0, 0, 0);

        // --- stage tile in per-wave LDS (no barrier: wave-private) ---
#pragma unroll
        for (int nt = 0; nt < 8; ++nt) {
            const int col = nt * 16 + c;
#pragma unroll
            for (int r = 0; r < 4; ++r)
                stage[wv][kb * 4 + r][col] = f2bf(acc[nt][r]);
        }
        // --- coalesced write-out: 4KB tile as dwordx4 ---
        uint4* dst4 = reinterpret_cast<uint4*>(AB + (size_t)n0 * 128);
        if (n0 + 16 <= nNodes) {
#pragma unroll
            for (int s2 = 0; s2 < 4; ++s2) {
                const int q = s2 * 64 + lane;
                dst4[q] = *reinterpret_cast<const uint4*>(&stage[wv][q >> 4][(q & 15) * 8]);
            }
        } else {
#pragma unroll
            for (int s2 = 0; s2 < 4; ++s2) {
                const int q = s2 * 64 + lane;
                if (n0 + (q >> 4) < nNodes)
                    dst4[q] = *reinterpret_cast<const uint4*>(&stage[wv][q >> 4][(q & 15) * 8]);
            }
        }
    }
}

__device__ __forceinline__ float edge_dot(const uint4 ua, const uint4 ub,
                                          const float* __restrict__ w2v) {
    float p = 0.f;
    const unsigned int au[4] = {ua.x, ua.y, ua.z, ua.w};
    const unsigned int bu[4] = {ub.x, ub.y, ub.z, ub.w};
#pragma unroll
    for (int i = 0; i < 4; ++i) {
        const float alo = __int_as_float((int)(au[i] << 16));
        const float ahi = __int_as_float((int)(au[i] & 0xffff0000u));
        const float blo = __int_as_float((int)(bu[i] << 16));
        const float bhi = __int_as_float((int)(bu[i] & 0xffff0000u));
        p = fmaf(fmaxf(alo + blo, 0.f), w2v[2 * i], p);
        p = fmaf(fmaxf(ahi + bhi, 0.f), w2v[2 * i + 1], p);
    }
    // reduce over the 8 lanes of this edge: sum accumulates at sub==7
    p += dpp_shr<1>(p);
    p += dpp_shr<2>(p);
    p += dpp_shr<4>(p);
    return p;
}

// 8 lanes/edge, 16 edges/wave-iter (two groups of 8). Each lane: one uint4
// (16B = 8 bf16) per operand; 8-lane groups read 128B contiguous segments.
// Indices prefetched one iteration ahead; nontemporal for streamed data.
__global__ __launch_bounds__(256) void edge_mlp(
    const int* __restrict__ ei, const unsigned int* __restrict__ AB,
    const float* __restrict__ W2, const float* __restrict__ b2,
    float* __restrict__ out, int nEdges, int totalWaves)
{
    const int lane = threadIdx.x & 63;
    const int sub  = lane & 7;
    const int grp  = lane >> 3;
    const int waveId = blockIdx.x * (blockDim.x >> 6) + (threadIdx.x >> 6);

    float w2v[8];
#pragma unroll
    for (int j = 0; j < 8; ++j) w2v[j] = W2[sub * 8 + j];
    const float b2s = b2[0];
    const int stride = totalWaves * 16;

    int base = waveId * 16;
    if (base >= nEdges) return;

    int eA = base + grp, eB = base + 8 + grp;
    int ecA = (eA < nEdges) ? eA : 0;
    int ecB = (eB < nEdges) ? eB : 0;
    int srcA = __builtin_nontemporal_load(ei + ecA);
    int dstA = __builtin_nontemporal_load(ei + nEdges + ecA);
    int srcB = __builtin_nontemporal_load(ei + ecB);
    int dstB = __builtin_nontemporal_load(ei + nEdges + ecB);

    while (true) {
        // issue all 4 gathers for this iteration immediately
        const uint4 uaA = *reinterpret_cast<const uint4*>(AB + (size_t)srcA * 64 + sub * 4);
        const uint4 ubA = *reinterpret_cast<const uint4*>(AB + (size_t)dstA * 64 + 32 + sub * 4);
        const uint4 uaB = *reinterpret_cast<const uint4*>(AB + (size_t)srcB * 64 + sub * 4);
        const uint4 ubB = *reinterpret_cast<const uint4*>(AB + (size_t)dstB * 64 + 32 + sub * 4);

        const int curA = base + grp, curB = base + 8 + grp;
        const int nbase = base + stride;

        if (nbase < nEdges) {   // prefetch next iteration's indices
            eA = nbase + grp;  eB = nbase + 8 + grp;
            ecA = (eA < nEdges) ? eA : 0;
            ecB = (eB < nEdges) ? eB : 0;
            srcA = __builtin_nontemporal_load(ei + ecA);
            dstA = __builtin_nontemporal_load(ei + nEdges + ecA);
            srcB = __builtin_nontemporal_load(ei + ecB);
            dstB = __builtin_nontemporal_load(ei + nEdges + ecB);
        }

        const float pA = edge_dot(uaA, ubA, w2v);
        const float pB = edge_dot(uaB, ubB, w2v);
        if (sub == 7) {
            if (curA < nEdges) __builtin_nontemporal_store(pA + b2s, out + curA);
            if (curB < nEdges) __builtin_nontemporal_store(pB + b2s, out + curB);
        }

        if (nbase >= nEdges) break;
        base = nbase;
    }
}

extern "C" void kernel_launch(void* const* d_in, const int* in_sizes, int n_in,
                              void* d_out, int out_size, void* d_ws, size_t ws_size,
                              hipStream_t stream) {
    const float* emb = (const float*)d_in[0];
    const int*   ei  = (const int*)d_in[1];
    const float* W1  = (const float*)d_in[2];
    const float* b1  = (const float*)d_in[3];
    const float* W2  = (const float*)d_in[4];
    const float* b2  = (const float*)d_in[5];
    float* out = (float*)d_out;
    unsigned short* AB = (unsigned short*)d_ws;   // nNodes*128 bf16 = 12.8 MB

    const int nNodes = in_sizes[0] / 64;   // 50000
    const int nEdges = in_sizes[1] / 2;    // 800000

    {
        // 128 blocks = 512 waves; 3125 tiles -> ~6 tiles/wave (setup amortized)
        const int blocks = 128;
        precompute_ab<<<blocks, 256, 0, stream>>>(emb, W1, b1, AB, nNodes, blocks * 4);
    }
    {
        // small VGPR -> full occupancy; 8192 waves, 16 edges/iter
        const int blocks = 2048;
        edge_mlp<<<blocks, 256, 0, stream>>>(ei, (const unsigned int*)AB, W2, b2,
                                             out, nEdges, blocks * 4);
    }
}

// Round 6
// 104.822 us; speedup vs baseline: 1.0374x; 1.0374x over previous
//
#include <hip/hip_runtime.h>
#include <hip/hip_bf16.h>

// PGExplainer edge-MLP:
//   logits[e] = relu(concat(emb[src], emb[dst]) @ W1 + b1) @ W2 + b2
// Restructured: A[n] = emb[n] @ W1[:64] + b1 ; B[n] = emb[n] @ W1[64:]
//   logits[e] = relu(A[src]+B[dst]) . W2 + b2
// AB[n*128 + j] bf16 (j<64 = A, j>=64 = B) lives in d_ws.
//
// R6 changes vs R5:
//  - edge: REVERT to R4 structure (8 edges/iter, pragma unroll 8 = 16 uint4
//    gathers in flight). R5's hand pipeline held only 4 gathers in flight ->
//    +14us regression on this latency-bound random gather. MLP depth is the
//    lever, not index prefetch.
//  - precompute: keep R5 LDS version (ds_read_b128 W1 frags, coalesced staged
//    stores) but 256 blocks (R5's 128 left half the CUs idle).

typedef __attribute__((ext_vector_type(8))) short bf16x8;
typedef __attribute__((ext_vector_type(4))) float f32x4;

__device__ __forceinline__ unsigned short f2bf(float f) {
    union { float f; unsigned int i; } v;
    v.f = f;
    unsigned int r = v.i + 0x7fffu + ((v.i >> 16) & 1u);  // RNE
    return (unsigned short)(r >> 16);
}

template <int N>
__device__ __forceinline__ float dpp_shr(float x) {
    return __int_as_float(__builtin_amdgcn_update_dpp(
        0, __float_as_int(x), 0x110 | N, 0xf, 0xf, true));
}

// MFMA GEMM: AB[50000 x 128] = E[50000 x 64] @ Wbig[64 x 128] (+ b1 cols<64)
// Wbig[k][j'] = j'<64 ? W1[k][j'] : W1[64+k][j'-64]
// Frag layouts (mfma_f32_16x16x32_bf16):
//   A: row = lane&15, k = (lane>>4)*8 + i (8 contiguous bf16)
//   B: col = lane&15, k = (lane>>4)*8 + i
//   D: col = lane&15, row = (lane>>4)*4 + reg   [verified m89]
__global__ __launch_bounds__(256) void precompute_ab(
    const float* __restrict__ emb, const float* __restrict__ W1,
    const float* __restrict__ b1, unsigned short* __restrict__ AB,
    int nNodes, int totalWaves)
{
    __shared__ unsigned short WT[128][72];        // WT[j'][k] bf16, pad to 72
    __shared__ unsigned short stage[4][16][136];  // per-wave 16x128 tile

    const int tid  = threadIdx.x;
    const int lane = tid & 63;
    const int wv   = tid >> 6;
    const int waveId = blockIdx.x * 4 + wv;
    const int c  = lane & 15;   // col selector (B/D), row selector (A)
    const int kb = lane >> 4;   // k-block 0..3

    // --- stage W1 transposed into LDS (coalesced float4 reads) ---
    for (int p = tid; p < 2048; p += 256) {       // 2048 float4s = 32KB
        const float4 v = reinterpret_cast<const float4*>(W1)[p];
        const int k  = p >> 4;          // 0..127 row of W1
        const int j0 = (p & 15) * 4;    // 0..60 col of W1
        const int kk2 = (k < 64) ? k : (k - 64);
        const int jo  = (k < 64) ? 0 : 64;
        WT[jo + j0 + 0][kk2] = f2bf(v.x);
        WT[jo + j0 + 1][kk2] = f2bf(v.y);
        WT[jo + j0 + 2][kk2] = f2bf(v.z);
        WT[jo + j0 + 3][kk2] = f2bf(v.w);
    }
    __syncthreads();

    // --- B fragments from LDS: aligned ds_read_b128 ---
    bf16x8 wfrag[8][2];
    float bias[8];
#pragma unroll
    for (int nt = 0; nt < 8; ++nt) {
        const int jp = nt * 16 + c;
        bias[nt] = (jp < 64) ? b1[jp] : 0.f;
#pragma unroll
        for (int kk = 0; kk < 2; ++kk)
            wfrag[nt][kk] = *reinterpret_cast<const bf16x8*>(&WT[jp][kk * 32 + kb * 8]);
    }

    const int nTiles = (nNodes + 15) >> 4;
    for (int t = waveId; t < nTiles; t += totalWaves) {
        const int n0 = t * 16;
        const int arow = n0 + c;
        const float* erow = emb + (size_t)((arow < nNodes) ? arow : (nNodes - 1)) * 64 + kb * 8;
        bf16x8 afrag[2];
#pragma unroll
        for (int kk = 0; kk < 2; ++kk) {
            const float4 f0 = *reinterpret_cast<const float4*>(erow + kk * 32);
            const float4 f1 = *reinterpret_cast<const float4*>(erow + kk * 32 + 4);
            afrag[kk][0] = (short)f2bf(f0.x); afrag[kk][1] = (short)f2bf(f0.y);
            afrag[kk][2] = (short)f2bf(f0.z); afrag[kk][3] = (short)f2bf(f0.w);
            afrag[kk][4] = (short)f2bf(f1.x); afrag[kk][5] = (short)f2bf(f1.y);
            afrag[kk][6] = (short)f2bf(f1.z); afrag[kk][7] = (short)f2bf(f1.w);
        }

        f32x4 acc[8];
#pragma unroll
        for (int nt = 0; nt < 8; ++nt) {
            acc[nt][0] = bias[nt]; acc[nt][1] = bias[nt];
            acc[nt][2] = bias[nt]; acc[nt][3] = bias[nt];
        }
#pragma unroll
        for (int kk = 0; kk < 2; ++kk)
#pragma unroll
            for (int nt = 0; nt < 8; ++nt)
                acc[nt] = __builtin_amdgcn_mfma_f32_16x16x32_bf16(
                    afrag[kk], wfrag[nt][kk], acc[nt], 0, 0, 0);

        // --- stage tile in per-wave LDS (wave-private, no barrier) ---
#pragma unroll
        for (int nt = 0; nt < 8; ++nt) {
            const int col = nt * 16 + c;
#pragma unroll
            for (int r = 0; r < 4; ++r)
                stage[wv][kb * 4 + r][col] = f2bf(acc[nt][r]);
        }
        // --- coalesced write-out: 4KB tile as dwordx4 ---
        uint4* dst4 = reinterpret_cast<uint4*>(AB + (size_t)n0 * 128);
        if (n0 + 16 <= nNodes) {
#pragma unroll
            for (int s2 = 0; s2 < 4; ++s2) {
                const int q = s2 * 64 + lane;
                dst4[q] = *reinterpret_cast<const uint4*>(&stage[wv][q >> 4][(q & 15) * 8]);
            }
        } else {
#pragma unroll
            for (int s2 = 0; s2 < 4; ++s2) {
                const int q = s2 * 64 + lane;
                if (n0 + (q >> 4) < nNodes)
                    dst4[q] = *reinterpret_cast<const uint4*>(&stage[wv][q >> 4][(q & 15) * 8]);
            }
        }
    }
}

// 8 lanes per edge, 8 edges per wave, unroll 8 (16 uint4 gathers in flight).
// Each lane: 8 hidden units via one uint4 (16B = 8 bf16) per operand; 8-lane
// groups read 128B contiguous segments. Reduce: 3 DPP row_shr adds -> sub==7.
__global__ __launch_bounds__(256) void edge_mlp(
    const int* __restrict__ ei, const unsigned int* __restrict__ AB,
    const float* __restrict__ W2, const float* __restrict__ b2,
    float* __restrict__ out, int nEdges, int totalWaves)
{
    const int lane = threadIdx.x & 63;
    const int sub  = lane & 7;    // hidden-chunk (8 units) within edge
    const int grp  = lane >> 3;   // which of the wave's 8 edges
    const int waveId = blockIdx.x * (blockDim.x >> 6) + (threadIdx.x >> 6);

    float w2v[8];
#pragma unroll
    for (int j = 0; j < 8; ++j) w2v[j] = W2[sub * 8 + j];
    const float b2s = b2[0];
    const int stride = totalWaves * 8;

#pragma unroll 8
    for (int base = waveId * 8; base < nEdges; base += stride) {
        const int e = base + grp;
        const bool valid = (e < nEdges);
        const int ec = valid ? e : 0;

        const int src = ei[ec];
        const int dst = ei[nEdges + ec];

        const uint4 ua = *reinterpret_cast<const uint4*>(AB + (size_t)src * 64 + sub * 4);
        const uint4 ub = *reinterpret_cast<const uint4*>(AB + (size_t)dst * 64 + 32 + sub * 4);

        float p = 0.f;
        const unsigned int au[4] = {ua.x, ua.y, ua.z, ua.w};
        const unsigned int bu[4] = {ub.x, ub.y, ub.z, ub.w};
#pragma unroll
        for (int i = 0; i < 4; ++i) {
            const float alo = __int_as_float((int)(au[i] << 16));
            const float ahi = __int_as_float((int)(au[i] & 0xffff0000u));
            const float blo = __int_as_float((int)(bu[i] << 16));
            const float bhi = __int_as_float((int)(bu[i] & 0xffff0000u));
            const float h0 = fmaxf(alo + blo, 0.f);
            const float h1 = fmaxf(ahi + bhi, 0.f);
            p = fmaf(h0, w2v[2 * i], p);
            p = fmaf(h1, w2v[2 * i + 1], p);
        }

        // reduce over the 8 lanes of this edge: sum accumulates at sub==7
        // (cross-group DPP contamination only reaches lanes never read).
        p += dpp_shr<1>(p);
        p += dpp_shr<2>(p);
        p += dpp_shr<4>(p);

        if (valid && sub == 7) out[e] = p + b2s;
    }
}

extern "C" void kernel_launch(void* const* d_in, const int* in_sizes, int n_in,
                              void* d_out, int out_size, void* d_ws, size_t ws_size,
                              hipStream_t stream) {
    const float* emb = (const float*)d_in[0];
    const int*   ei  = (const int*)d_in[1];
    const float* W1  = (const float*)d_in[2];
    const float* b1  = (const float*)d_in[3];
    const float* W2  = (const float*)d_in[4];
    const float* b2  = (const float*)d_in[5];
    float* out = (float*)d_out;
    unsigned short* AB = (unsigned short*)d_ws;   // nNodes*128 bf16 = 12.8 MB

    const int nNodes = in_sizes[0] / 64;   // 50000
    const int nEdges = in_sizes[1] / 2;    // 800000

    {
        // 256 blocks = 1024 waves on 256 CUs; 3125 tiles -> ~3 tiles/wave
        const int blocks = 256;
        precompute_ab<<<blocks, 256, 0, stream>>>(emb, W1, b1, AB, nNodes, blocks * 4);
    }
    {
        // small VGPR -> full occupancy; 8192 waves, 8 edges/iter, unroll 8
        const int blocks = 2048;
        edge_mlp<<<blocks, 256, 0, stream>>>(ei, (const unsigned int*)AB, W2, b2,
                                             out, nEdges, blocks * 4);
    }
}